// Round 1
// baseline (7121.618 us; speedup 1.0000x reference)
//
#include <hip/hip_runtime.h>
#include <hip/hip_bf16.h>
#include <math.h>

// Model dims (B=1)
#define S 1024
#define D 768
#define L 12
#define NH 24
#define DK 32
#define DV 32
#define QKV_OUT 2304   // NH*(DK+DK+DV)
#define FF1_OUT 1536   // 2*D
#define V_SZ 50304

__device__ __forceinline__ float logaddexp_f(float a, float b) {
    float mx = fmaxf(a, b);
    float mn = fminf(a, b);
    return mx + log1pf(expf(mn - mx));
}

__device__ __forceinline__ float log_sigmoid_f(float x) {
    // min(x,0) - log1p(exp(-|x|))
    return fminf(x, 0.f) - log1pf(expf(-fabsf(x)));
}

// ---------------------------------------------------------------- embedding
__global__ __launch_bounds__(256) void embed_kernel(
    const int* __restrict__ tok, const float* __restrict__ ew, float* __restrict__ x) {
    int t = blockIdx.x;
    int id = tok[t];
    const float* src = ew + (size_t)id * D;
    float* dst = x + (size_t)t * D;
    for (int d = threadIdx.x; d < D; d += 256) dst[d] = src[d];
}

// ----------------------------------------------------- position gated scan
// h: (S, 1536) = [pre-sigmoid gates | logits]; x += rec (in place)
__global__ __launch_bounds__(256) void pos_scan_kernel(
    const float* __restrict__ h, float* __restrict__ x) {
    int d = blockIdx.x * 256 + threadIdx.x;  // 0..767
    if (d >= D) return;
    float rec = 0.f;
    for (int t = 0; t < S; ++t) {
        float g  = h[(size_t)t * FF1_OUT + d];
        float lg = h[(size_t)t * FF1_OUT + D + d];
        rec = logaddexp_f(rec + log_sigmoid_f(g), lg);
        x[(size_t)t * D + d] += rec;
    }
}

// ---------------------------------------------------------------- layernorm
__global__ __launch_bounds__(256) void ln_kernel(
    const float* __restrict__ in, const float* __restrict__ g,
    const float* __restrict__ b, float* __restrict__ out) {
    int row = blockIdx.x;
    int tid = threadIdx.x;
    const float* p = in + (size_t)row * D;
    float v0 = p[tid], v1 = p[tid + 256], v2 = p[tid + 512];

    __shared__ float red[8];
    float s = v0 + v1 + v2;
    #pragma unroll
    for (int o = 32; o > 0; o >>= 1) s += __shfl_down(s, o, 64);
    int wave = tid >> 6, lane = tid & 63;
    if (lane == 0) red[wave] = s;
    __syncthreads();
    float mean = (red[0] + red[1] + red[2] + red[3]) * (1.f / (float)D);

    float d0 = v0 - mean, d1 = v1 - mean, d2 = v2 - mean;
    float ss = d0 * d0 + d1 * d1 + d2 * d2;
    #pragma unroll
    for (int o = 32; o > 0; o >>= 1) ss += __shfl_down(ss, o, 64);
    if (lane == 0) red[4 + wave] = ss;
    __syncthreads();
    float var = (red[4] + red[5] + red[6] + red[7]) * (1.f / (float)D);
    float rstd = rsqrtf(var + 1e-5f);

    float* o = out + (size_t)row * D;
    o[tid]       = d0 * rstd * g[tid]       + b[tid];
    o[tid + 256] = d1 * rstd * g[tid + 256] + b[tid + 256];
    o[tid + 512] = d2 * rstd * g[tid + 512] + b[tid + 512];
}

// ------------------------------------------------------------------ matmul
// C[M,N] = A[M,K] @ B + bias + Cin.  BT=false: B is (K,N); BT=true: B is (N,K).
// Requires M%64==0, N%64==0, K%16==0.
template <bool BT>
__global__ __launch_bounds__(256) void matmul_kernel(
    const float* __restrict__ A, const float* __restrict__ B,
    const float* __restrict__ bias, const float* __restrict__ Cin,
    float* __restrict__ C, int M, int N, int K) {
    __shared__ __align__(16) float As[16][68];
    __shared__ __align__(16) float Bs[16][68];
    int tl = threadIdx.x;
    int tx = tl & 15, ty = tl >> 4;
    int m0 = blockIdx.y * 64, n0 = blockIdx.x * 64;

    float acc[4][4] = {};

    for (int k0 = 0; k0 < K; k0 += 16) {
        #pragma unroll
        for (int i = 0; i < 4; i++) {
            int idx = tl + i * 256;
            int r = idx >> 4, c = idx & 15;
            As[c][r] = A[(size_t)(m0 + r) * K + k0 + c];
        }
        if (!BT) {
            #pragma unroll
            for (int i = 0; i < 4; i++) {
                int idx = tl + i * 256;
                int r = idx >> 6, c = idx & 63;
                Bs[r][c] = B[(size_t)(k0 + r) * N + n0 + c];
            }
        } else {
            #pragma unroll
            for (int i = 0; i < 4; i++) {
                int idx = tl + i * 256;
                int r = idx >> 4, c = idx & 15;
                Bs[c][r] = B[(size_t)(n0 + r) * K + k0 + c];
            }
        }
        __syncthreads();
        #pragma unroll
        for (int k = 0; k < 16; k++) {
            float4 a4 = *(const float4*)&As[k][ty * 4];
            float4 b4 = *(const float4*)&Bs[k][tx * 4];
            float a[4] = {a4.x, a4.y, a4.z, a4.w};
            float b[4] = {b4.x, b4.y, b4.z, b4.w};
            #pragma unroll
            for (int i = 0; i < 4; i++)
                #pragma unroll
                for (int j = 0; j < 4; j++)
                    acc[i][j] = fmaf(a[i], b[j], acc[i][j]);
        }
        __syncthreads();
    }

    #pragma unroll
    for (int i = 0; i < 4; i++) {
        int m = m0 + ty * 4 + i;
        size_t off = (size_t)m * N + n0 + tx * 4;
        float4 v = make_float4(acc[i][0], acc[i][1], acc[i][2], acc[i][3]);
        if (bias) {
            const float4 bb = *(const float4*)(bias + n0 + tx * 4);
            v.x += bb.x; v.y += bb.y; v.z += bb.z; v.w += bb.w;
        }
        if (Cin) {
            const float4 cc = *(const float4*)(Cin + off);
            v.x += cc.x; v.y += cc.y; v.z += cc.z; v.w += cc.w;
        }
        *(float4*)(C + off) = v;
    }
}

// --------------------------------------------------------------- attention
// Linear-space causal attention with exp features.
// y: (S, 2304) rows = per-token [Q|K|V] x 24 heads of 96.
// att: (S, 768), att[t, h*32+j] = log(S[t,j]) - log(Z[t]).
__global__ __launch_bounds__(64) void attn_kernel(
    const float* __restrict__ y, float* __restrict__ att) {
    int tb = blockIdx.x;     // t tile (16 tiles of 64)
    int head = blockIdx.y;   // 24 heads
    int tid = threadIdx.x;   // 64 threads, one t-row each
    int t = tb * 64 + tid;

    const float* yq = y + (size_t)t * QKV_OUT + head * 96;
    float eq[DK];
    #pragma unroll
    for (int j = 0; j < DK; j += 4) {
        float4 q = *(const float4*)(yq + j);
        eq[j] = expf(q.x); eq[j + 1] = expf(q.y);
        eq[j + 2] = expf(q.z); eq[j + 3] = expf(q.w);
    }

    float acc[DV] = {};
    float zsum = 0.f;

    __shared__ __align__(16) float ek[64][36];
    __shared__ __align__(16) float ev[64][36];

    for (int sb = 0; sb <= tb; ++sb) {
        const float* ys = y + (size_t)(sb * 64 + tid) * QKV_OUT + head * 96;
        #pragma unroll
        for (int j = 0; j < DK; j += 4) {
            float4 k4 = *(const float4*)(ys + 32 + j);
            float4 v4 = *(const float4*)(ys + 64 + j);
            ek[tid][j] = expf(k4.x); ek[tid][j + 1] = expf(k4.y);
            ek[tid][j + 2] = expf(k4.z); ek[tid][j + 3] = expf(k4.w);
            ev[tid][j] = expf(v4.x); ev[tid][j + 1] = expf(v4.y);
            ev[tid][j + 2] = expf(v4.z); ev[tid][j + 3] = expf(v4.w);
        }
        __syncthreads();
        int send = (sb == tb) ? (tid + 1) : 64;
        for (int si = 0; si < send; ++si) {
            const float4* ekr = (const float4*)ek[si];
            float d0 = 0.f, d1 = 0.f, d2 = 0.f, d3 = 0.f;
            #pragma unroll
            for (int jj = 0; jj < 8; jj++) {
                float4 k4 = ekr[jj];
                d0 = fmaf(eq[jj * 4 + 0], k4.x, d0);
                d1 = fmaf(eq[jj * 4 + 1], k4.y, d1);
                d2 = fmaf(eq[jj * 4 + 2], k4.z, d2);
                d3 = fmaf(eq[jj * 4 + 3], k4.w, d3);
            }
            float a = (d0 + d1) + (d2 + d3);
            zsum += a;
            const float4* evr = (const float4*)ev[si];
            #pragma unroll
            for (int jj = 0; jj < 8; jj++) {
                float4 v4 = evr[jj];
                acc[jj * 4 + 0] = fmaf(a, v4.x, acc[jj * 4 + 0]);
                acc[jj * 4 + 1] = fmaf(a, v4.y, acc[jj * 4 + 1]);
                acc[jj * 4 + 2] = fmaf(a, v4.z, acc[jj * 4 + 2]);
                acc[jj * 4 + 3] = fmaf(a, v4.w, acc[jj * 4 + 3]);
            }
        }
        __syncthreads();
    }

    float lz = logf(zsum);
    float* po = att + (size_t)t * D + head * DV;
    #pragma unroll
    for (int j = 0; j < DV; j++) po[j] = logf(acc[j]) - lz;
}

// --------------------------------------------------------------------- GLU
__global__ __launch_bounds__(256) void glu_kernel(
    const float* __restrict__ z, float* __restrict__ zg) {
    int idx = blockIdx.x * 256 + threadIdx.x;  // < S*D
    int t = idx / D, d = idx - t * D;
    float a = z[(size_t)t * FF1_OUT + d];
    float g = z[(size_t)t * FF1_OUT + D + d];
    zg[idx] = a * (1.f / (1.f + expf(-g)));
}

// ------------------------------------------------------------------ launch
extern "C" void kernel_launch(void* const* d_in, const int* in_sizes, int n_in,
                              void* d_out, int out_size, void* d_ws, size_t ws_size,
                              hipStream_t stream) {
    const int*   tok     = (const int*)d_in[0];
    const float* embed_w = (const float*)d_in[1];
    const float* pos_w   = (const float*)d_in[2];
    const float* pos_b   = (const float*)d_in[3];
    const float* ln1_g   = (const float*)d_in[4];
    const float* ln1_b   = (const float*)d_in[5];
    const float* qkv_w   = (const float*)d_in[6];
    const float* qkv_b   = (const float*)d_in[7];
    const float* ff_w1   = (const float*)d_in[8];
    const float* ff_b1   = (const float*)d_in[9];
    const float* ff_w2   = (const float*)d_in[10];
    const float* lnf_g   = (const float*)d_in[11];
    const float* lnf_b   = (const float*)d_in[12];
    float* out = (float*)d_out;

    float* ws = (float*)d_ws;
    float* X   = ws;                 // S*D
    float* LNX = ws + 786432;        // S*D
    float* Y   = ws + 1572864;       // S*QKV_OUT (aliases h and z)
    float* ATT = ws + 3932160;       // S*D
    float* ZG  = ws + 4718592;       // S*D

    // x = embed_w[token_ids]
    embed_kernel<<<S, 256, 0, stream>>>(tok, embed_w, X);

    // h = x @ pos_w + pos_b ; x += gated log-space scan(h)
    matmul_kernel<false><<<dim3(FF1_OUT / 64, S / 64), 256, 0, stream>>>(
        X, pos_w, pos_b, nullptr, Y, S, FF1_OUT, D);
    pos_scan_kernel<<<3, 256, 0, stream>>>(Y, X);

    for (int l = 0; l < L; ++l) {
        // ln1
        ln_kernel<<<S, 256, 0, stream>>>(X, ln1_g + (size_t)l * D, ln1_b + (size_t)l * D, LNX);
        // y = lnx @ qkv_w[l] + qkv_b[l]
        matmul_kernel<false><<<dim3(QKV_OUT / 64, S / 64), 256, 0, stream>>>(
            LNX, qkv_w + (size_t)l * D * QKV_OUT, qkv_b + (size_t)l * QKV_OUT, nullptr,
            Y, S, QKV_OUT, D);
        // att
        attn_kernel<<<dim3(S / 64, NH), 64, 0, stream>>>(Y, ATT);
        // z = att @ ff_w1[l] + ff_b1[l]   (z overwrites Y)
        matmul_kernel<false><<<dim3(FF1_OUT / 64, S / 64), 256, 0, stream>>>(
            ATT, ff_w1 + (size_t)l * (NH * DV) * FF1_OUT, ff_b1 + (size_t)l * FF1_OUT, nullptr,
            Y, S, FF1_OUT, NH * DV);
        // zg = z[:, :D] * sigmoid(z[:, D:])
        glu_kernel<<<(S * D) / 256, 256, 0, stream>>>(Y, ZG);
        // x = x + zg @ ff_w2[l]
        matmul_kernel<false><<<dim3(D / 64, S / 64), 256, 0, stream>>>(
            ZG, ff_w2 + (size_t)l * D * D, nullptr, X, X, S, D, D);
    }

    // final LN + vocab projection out = lnx @ embed_w^T
    ln_kernel<<<S, 256, 0, stream>>>(X, lnf_g, lnf_b, LNX);
    matmul_kernel<true><<<dim3(V_SZ / 64, S / 64), 256, 0, stream>>>(
        LNX, embed_w, nullptr, nullptr, out, S, V_SZ, D);
}

// Round 2
// 3341.869 us; speedup vs baseline: 2.1310x; 2.1310x over previous
//
#include <hip/hip_runtime.h>
#include <math.h>

#define S 1024
#define D 768
#define L 12
#define NH 24
#define QKV_OUT 2304
#define FF1_OUT 1536
#define V_SZ 50304

typedef unsigned short u16;
typedef __attribute__((ext_vector_type(8))) short bf16x8;
typedef __attribute__((ext_vector_type(4))) float f32x4;

__device__ __forceinline__ u16 f2bf(float x) {
    unsigned u = __float_as_uint(x);
    u += 0x7fffu + ((u >> 16) & 1u);
    return (u16)(u >> 16);
}

__device__ __forceinline__ void async_copy16(const void* g, void* l) {
    __builtin_amdgcn_global_load_lds(
        (const __attribute__((address_space(1))) unsigned int*)g,
        (__attribute__((address_space(3))) unsigned int*)l, 16, 0, 0);
}

__device__ __forceinline__ float logaddexp_f(float a, float b) {
    float mx = fmaxf(a, b);
    float mn = fminf(a, b);
    return mx + log1pf(expf(mn - mx));
}

__device__ __forceinline__ float log_sigmoid_f(float x) {
    return fminf(x, 0.f) - log1pf(expf(-fabsf(x)));
}

// ---------------------------------------------------------------- embedding
__global__ __launch_bounds__(256) void embed_kernel(
    const int* __restrict__ tok, const float* __restrict__ ew,
    float* __restrict__ x, u16* __restrict__ xb) {
    int t = blockIdx.x;
    int id = tok[t];
    const float* src = ew + (size_t)id * D;
    for (int d = threadIdx.x; d < D; d += 256) {
        float v = src[d];
        x[(size_t)t * D + d] = v;
        xb[(size_t)t * D + d] = f2bf(v);
    }
}

// ----------------------------------------------------- position gated scan
__global__ __launch_bounds__(256) void pos_scan_kernel(
    const float* __restrict__ h, float* __restrict__ x) {
    int d = blockIdx.x * 256 + threadIdx.x;
    if (d >= D) return;
    float rec = 0.f;
    for (int t = 0; t < S; ++t) {
        float g  = h[(size_t)t * FF1_OUT + d];
        float lg = h[(size_t)t * FF1_OUT + D + d];
        rec = logaddexp_f(rec + log_sigmoid_f(g), lg);
        x[(size_t)t * D + d] += rec;
    }
}

// ---------------------------------------------------- layernorm (bf16 out)
__global__ __launch_bounds__(256) void ln_kernel(
    const float* __restrict__ in, const float* __restrict__ g,
    const float* __restrict__ b, u16* __restrict__ out) {
    int row = blockIdx.x;
    int tid = threadIdx.x;
    const float* p = in + (size_t)row * D;
    float v0 = p[tid], v1 = p[tid + 256], v2 = p[tid + 512];

    __shared__ float red[8];
    float s = v0 + v1 + v2;
    #pragma unroll
    for (int o = 32; o > 0; o >>= 1) s += __shfl_down(s, o, 64);
    int wave = tid >> 6, lane = tid & 63;
    if (lane == 0) red[wave] = s;
    __syncthreads();
    float mean = (red[0] + red[1] + red[2] + red[3]) * (1.f / (float)D);

    float d0 = v0 - mean, d1 = v1 - mean, d2 = v2 - mean;
    float ss = d0 * d0 + d1 * d1 + d2 * d2;
    #pragma unroll
    for (int o = 32; o > 0; o >>= 1) ss += __shfl_down(ss, o, 64);
    if (lane == 0) red[4 + wave] = ss;
    __syncthreads();
    float var = (red[4] + red[5] + red[6] + red[7]) * (1.f / (float)D);
    float rstd = rsqrtf(var + 1e-5f);

    u16* o = out + (size_t)row * D;
    o[tid]       = f2bf(d0 * rstd * g[tid]       + b[tid]);
    o[tid + 256] = f2bf(d1 * rstd * g[tid + 256] + b[tid + 256]);
    o[tid + 512] = f2bf(d2 * rstd * g[tid + 512] + b[tid + 512]);
}

// ------------------------------------- weight convert+transpose fp32->bf16
// W: (768, N) fp32 -> WT: (N, 768) bf16.  grid (N/32, 24, nmat)
__global__ __launch_bounds__(256) void wconv_kernel(
    const float* __restrict__ W, u16* __restrict__ WT, int N) {
    __shared__ float tile[32][33];
    const int z = blockIdx.z;
    W  += (size_t)z * 768 * N;
    WT += (size_t)z * N * 768;
    const int n0 = blockIdx.x * 32, k0 = blockIdx.y * 32;
    const int t = threadIdx.x;
    const int r = t >> 3, c4 = (t & 7) * 4;
    float4 v = *(const float4*)(W + (size_t)(k0 + r) * N + n0 + c4);
    tile[r][c4] = v.x; tile[r][c4 + 1] = v.y; tile[r][c4 + 2] = v.z; tile[r][c4 + 3] = v.w;
    __syncthreads();
    ushort4 o;
    o.x = f2bf(tile[c4][r]);     o.y = f2bf(tile[c4 + 1][r]);
    o.z = f2bf(tile[c4 + 2][r]); o.w = f2bf(tile[c4 + 3][r]);
    *(ushort4*)(WT + (size_t)(n0 + r) * 768 + k0 + c4) = o;
}

// ------------------------------------------------------------- MFMA GEMM
// C[M,N](fp32) = A[M,768](bf16) @ B^T  (+bias) (+Cin).
// B is (N,768): bf16 if BF16B else fp32 (inline convert).
// grid (N/128, M/128), 256 threads.
template <bool BF16B>
__global__ __launch_bounds__(256) void gemm_kernel(
    const u16* __restrict__ A, const void* __restrict__ Bv,
    const float* __restrict__ bias, const float* __restrict__ Cin,
    float* __restrict__ C, int N) {
    constexpr int K = 768;
    __shared__ __align__(16) u16 As[128 * 32];
    __shared__ __align__(16) u16 Bs[128 * 32];
    const int tid = threadIdx.x;
    const int w = tid >> 6, lane = tid & 63;
    const int m0 = blockIdx.y * 128, n0 = blockIdx.x * 128;
    const int wm = (w >> 1) * 64, wn = (w & 1) * 64;

    f32x4 acc[4][4] = {};

    const int rA = w * 32 + (lane >> 2);     // staged row (+16 for 2nd call)
    const int cA = (lane & 3) * 8;           // k element offset (8 bf16 = 16B)
    const int frow = lane & 15;
    const int fko = (lane >> 4) * 8;

    for (int k0 = 0; k0 < K; k0 += 32) {
        // ---- stage A (async, 16B/lane)
        {
            const u16* g0 = A + (size_t)(m0 + rA) * K + k0 + cA;
            async_copy16(g0, (char*)As + w * 2048);
            async_copy16(g0 + (size_t)16 * K, (char*)As + w * 2048 + 1024);
        }
        // ---- stage B
        if (BF16B) {
            const u16* B = (const u16*)Bv;
            const u16* g0 = B + (size_t)(n0 + rA) * K + k0 + cA;
            async_copy16(g0, (char*)Bs + w * 2048);
            async_copy16(g0 + (size_t)16 * K, (char*)Bs + w * 2048 + 1024);
        } else {
            const float* B = (const float*)Bv;
            const int r = tid >> 1, half = tid & 1;
            const float* src = B + (size_t)(n0 + r) * K + k0 + half * 16;
            float4 v0 = *(const float4*)(src);
            float4 v1 = *(const float4*)(src + 4);
            float4 v2 = *(const float4*)(src + 8);
            float4 v3 = *(const float4*)(src + 12);
            unsigned p0 = (unsigned)f2bf(v0.x) | ((unsigned)f2bf(v0.y) << 16);
            unsigned p1 = (unsigned)f2bf(v0.z) | ((unsigned)f2bf(v0.w) << 16);
            unsigned p2 = (unsigned)f2bf(v1.x) | ((unsigned)f2bf(v1.y) << 16);
            unsigned p3 = (unsigned)f2bf(v1.z) | ((unsigned)f2bf(v1.w) << 16);
            unsigned p4 = (unsigned)f2bf(v2.x) | ((unsigned)f2bf(v2.y) << 16);
            unsigned p5 = (unsigned)f2bf(v2.z) | ((unsigned)f2bf(v2.w) << 16);
            unsigned p6 = (unsigned)f2bf(v3.x) | ((unsigned)f2bf(v3.y) << 16);
            unsigned p7 = (unsigned)f2bf(v3.z) | ((unsigned)f2bf(v3.w) << 16);
            u16* dst = Bs + r * 32 + half * 16;
            *(uint4*)(dst)     = make_uint4(p0, p1, p2, p3);
            *(uint4*)(dst + 8) = make_uint4(p4, p5, p6, p7);
        }
        __syncthreads();

        bf16x8 af[4], bfr[4];
        #pragma unroll
        for (int i = 0; i < 4; ++i)
            af[i] = *(const bf16x8*)(As + (wm + i * 16 + frow) * 32 + fko);
        #pragma unroll
        for (int j = 0; j < 4; ++j)
            bfr[j] = *(const bf16x8*)(Bs + (wn + j * 16 + frow) * 32 + fko);
        #pragma unroll
        for (int i = 0; i < 4; ++i)
            #pragma unroll
            for (int j = 0; j < 4; ++j)
                acc[i][j] = __builtin_amdgcn_mfma_f32_16x16x32_bf16(af[i], bfr[j], acc[i][j], 0, 0, 0);
        __syncthreads();
    }

    const int crow = wm + (lane >> 4) * 4;
    const int ccol = wn + (lane & 15);
    #pragma unroll
    for (int j = 0; j < 4; ++j) {
        int col = n0 + ccol + j * 16;
        float bj = bias ? bias[col] : 0.f;
        #pragma unroll
        for (int i = 0; i < 4; ++i) {
            #pragma unroll
            for (int r = 0; r < 4; ++r) {
                int row = m0 + crow + i * 16 + r;
                size_t off = (size_t)row * N + col;
                float v = acc[i][j][r] + bj;
                if (Cin) v += Cin[off];
                C[off] = v;
            }
        }
    }
}

// --------------------------------------------------------------- attention
// Linear-space causal attention with exp features, 4-wave s-block split.
__global__ __launch_bounds__(256) void attn_kernel(
    const float* __restrict__ y, u16* __restrict__ att) {
    const int tb = blockIdx.x, head = blockIdx.y;
    const int tid = threadIdx.x, w = tid >> 6, lane = tid & 63;
    const int t = tb * 64 + lane;

    __shared__ __align__(16) float ek[4][64][36];
    __shared__ __align__(16) float ev[4][64][36];

    const float* yq = y + (size_t)t * QKV_OUT + head * 96;
    float eq[32];
    #pragma unroll
    for (int j = 0; j < 32; j += 4) {
        float4 q = *(const float4*)(yq + j);
        eq[j] = __expf(q.x); eq[j + 1] = __expf(q.y);
        eq[j + 2] = __expf(q.z); eq[j + 3] = __expf(q.w);
    }

    float acc[32] = {};
    float zsum = 0.f;
    float* ekw = &ek[w][0][0];
    float* evw = &ev[w][0][0];

    for (int sb = w; sb <= tb; sb += 4) {
        const float* ys = y + (size_t)(sb * 64 + lane) * QKV_OUT + head * 96;
        #pragma unroll
        for (int j = 0; j < 32; j += 4) {
            float4 k4 = *(const float4*)(ys + 32 + j);
            float4 v4 = *(const float4*)(ys + 64 + j);
            ekw[lane * 36 + j]     = __expf(k4.x);
            ekw[lane * 36 + j + 1] = __expf(k4.y);
            ekw[lane * 36 + j + 2] = __expf(k4.z);
            ekw[lane * 36 + j + 3] = __expf(k4.w);
            evw[lane * 36 + j]     = __expf(v4.x);
            evw[lane * 36 + j + 1] = __expf(v4.y);
            evw[lane * 36 + j + 2] = __expf(v4.z);
            evw[lane * 36 + j + 3] = __expf(v4.w);
        }
        // same-wave DS ordering: writes retire before subsequent reads issue
        int send = (sb == tb) ? (lane + 1) : 64;
        for (int si = 0; si < send; ++si) {
            const float4* ekr = (const float4*)(ekw + si * 36);
            float d0 = 0.f, d1 = 0.f, d2 = 0.f, d3 = 0.f;
            #pragma unroll
            for (int jj = 0; jj < 8; ++jj) {
                float4 k4 = ekr[jj];
                d0 = fmaf(eq[jj * 4 + 0], k4.x, d0);
                d1 = fmaf(eq[jj * 4 + 1], k4.y, d1);
                d2 = fmaf(eq[jj * 4 + 2], k4.z, d2);
                d3 = fmaf(eq[jj * 4 + 3], k4.w, d3);
            }
            float a = (d0 + d1) + (d2 + d3);
            zsum += a;
            const float4* evr = (const float4*)(evw + si * 36);
            #pragma unroll
            for (int jj = 0; jj < 8; ++jj) {
                float4 v4 = evr[jj];
                acc[jj * 4 + 0] = fmaf(a, v4.x, acc[jj * 4 + 0]);
                acc[jj * 4 + 1] = fmaf(a, v4.y, acc[jj * 4 + 1]);
                acc[jj * 4 + 2] = fmaf(a, v4.z, acc[jj * 4 + 2]);
                acc[jj * 4 + 3] = fmaf(a, v4.w, acc[jj * 4 + 3]);
            }
        }
    }
    __syncthreads();
    float* red = &ek[0][0][0];  // [4][64][33] reuse
    #pragma unroll
    for (int j = 0; j < 32; ++j) red[(w * 64 + lane) * 33 + j] = acc[j];
    red[(w * 64 + lane) * 33 + 32] = zsum;
    __syncthreads();
    float zs = red[lane * 33 + 32] + red[(64 + lane) * 33 + 32] +
               red[(128 + lane) * 33 + 32] + red[(192 + lane) * 33 + 32];
    float lz = __logf(zs);
    u16* po = att + (size_t)(tb * 64 + lane) * D + head * 32;
    #pragma unroll
    for (int jj = 0; jj < 8; ++jj) {
        int j = w * 8 + jj;
        float s = red[lane * 33 + j] + red[(64 + lane) * 33 + j] +
                  red[(128 + lane) * 33 + j] + red[(192 + lane) * 33 + j];
        po[j] = f2bf(__logf(s) - lz);
    }
}

// --------------------------------------------------------------------- GLU
__global__ __launch_bounds__(256) void glu_kernel(
    const float* __restrict__ z, u16* __restrict__ zg) {
    int idx = blockIdx.x * 256 + threadIdx.x;
    int t = idx / D, d = idx - t * D;
    float a = z[(size_t)t * FF1_OUT + d];
    float g = z[(size_t)t * FF1_OUT + D + d];
    zg[idx] = f2bf(a * (1.f / (1.f + __expf(-g))));
}

// ------------------------------------------------------------------ launch
extern "C" void kernel_launch(void* const* d_in, const int* in_sizes, int n_in,
                              void* d_out, int out_size, void* d_ws, size_t ws_size,
                              hipStream_t stream) {
    const int*   tok     = (const int*)d_in[0];
    const float* embed_w = (const float*)d_in[1];
    const float* pos_w   = (const float*)d_in[2];
    const float* pos_b   = (const float*)d_in[3];
    const float* ln1_g   = (const float*)d_in[4];
    const float* ln1_b   = (const float*)d_in[5];
    const float* qkv_w   = (const float*)d_in[6];
    const float* qkv_b   = (const float*)d_in[7];
    const float* ff_w1   = (const float*)d_in[8];
    const float* ff_b1   = (const float*)d_in[9];
    const float* ff_w2   = (const float*)d_in[10];
    const float* lnf_g   = (const float*)d_in[11];
    const float* lnf_b   = (const float*)d_in[12];
    float* out = (float*)d_out;

    char* base = (char*)d_ws;
    float* X    = (float*)(base);                 // 3,145,728 B
    u16*   XB   = (u16*)  (base + 3145728);       // 1,572,864
    float* Y    = (float*)(base + 4718592);       // 9,437,184
    u16*   LNX  = (u16*)  (base + 14155776);      // 1,572,864
    u16*   ATT  = (u16*)  (base + 15728640);      // 1,572,864
    u16*   ZG   = (u16*)  (base + 17301504);      // 1,572,864
    u16*   posT = (u16*)  (base + 18874368);      // 2,359,296
    u16*   qkvT = (u16*)  (base + 21233664);      // 42,467,328
    u16*   ff1T = (u16*)  (base + 63700992);      // 28,311,552
    u16*   ff2T = (u16*)  (base + 92012544);      // 14,155,776  (end 106,168,320)

    // weight convert+transpose (per call; deterministic)
    wconv_kernel<<<dim3(48, 24, 1),  256, 0, stream>>>(pos_w, posT, 1536);
    wconv_kernel<<<dim3(72, 24, 12), 256, 0, stream>>>(qkv_w, qkvT, 2304);
    wconv_kernel<<<dim3(48, 24, 12), 256, 0, stream>>>(ff_w1, ff1T, 1536);
    wconv_kernel<<<dim3(24, 24, 12), 256, 0, stream>>>(ff_w2, ff2T, 768);

    embed_kernel<<<S, 256, 0, stream>>>(tok, embed_w, X, XB);

    gemm_kernel<true><<<dim3(12, 8), 256, 0, stream>>>(XB, posT, pos_b, nullptr, Y, FF1_OUT);
    pos_scan_kernel<<<3, 256, 0, stream>>>(Y, X);

    for (int l = 0; l < L; ++l) {
        ln_kernel<<<S, 256, 0, stream>>>(X, ln1_g + (size_t)l * D, ln1_b + (size_t)l * D, LNX);
        gemm_kernel<true><<<dim3(18, 8), 256, 0, stream>>>(
            LNX, qkvT + (size_t)l * QKV_OUT * 768, qkv_b + (size_t)l * QKV_OUT, nullptr, Y, QKV_OUT);
        attn_kernel<<<dim3(16, NH), 256, 0, stream>>>(Y, ATT);
        gemm_kernel<true><<<dim3(12, 8), 256, 0, stream>>>(
            ATT, ff1T + (size_t)l * FF1_OUT * 768, ff_b1 + (size_t)l * FF1_OUT, nullptr, Y, FF1_OUT);
        glu_kernel<<<(S * D) / 256, 256, 0, stream>>>(Y, ZG);
        gemm_kernel<true><<<dim3(6, 8), 256, 0, stream>>>(
            ZG, ff2T + (size_t)l * D * 768, nullptr, X, X, D);
    }

    ln_kernel<<<S, 256, 0, stream>>>(X, lnf_g, lnf_b, LNX);
    gemm_kernel<false><<<dim3(393, 8), 256, 0, stream>>>(LNX, embed_w, nullptr, nullptr, out, V_SZ);
}

// Round 3
// 1907.698 us; speedup vs baseline: 3.7331x; 1.7518x over previous
//
#include <hip/hip_runtime.h>
#include <math.h>

#define S 1024
#define D 768
#define L 12
#define NH 24
#define QKV_OUT 2304
#define FF1_OUT 1536
#define V_SZ 50304

typedef unsigned short u16;
typedef __attribute__((ext_vector_type(8))) short bf16x8;
typedef __attribute__((ext_vector_type(4))) float f32x4;

__device__ __forceinline__ u16 f2bf(float x) {
    unsigned u = __float_as_uint(x);
    u += 0x7fffu + ((u >> 16) & 1u);
    return (u16)(u >> 16);
}

__device__ __forceinline__ void async_copy16(const void* g, void* l) {
    __builtin_amdgcn_global_load_lds(
        (const __attribute__((address_space(1))) unsigned int*)g,
        (__attribute__((address_space(3))) unsigned int*)l, 16, 0, 0);
}

// ---------------------------------------------------------------- embedding
__global__ __launch_bounds__(256) void embed_kernel(
    const int* __restrict__ tok, const float* __restrict__ ew,
    float* __restrict__ x, u16* __restrict__ xb) {
    int t = blockIdx.x;
    int id = tok[t];
    const float* src = ew + (size_t)id * D;
    for (int d = threadIdx.x; d < D; d += 256) {
        float v = src[d];
        x[(size_t)t * D + d] = v;
        xb[(size_t)t * D + d] = f2bf(v);
    }
}

// ------------------------------------------- position scan (parallel, linear)
// R_t = R_{t-1} * sigmoid(g_t) + exp(lg_t), R_{-1}=1; x[t] += log(R_t).
// One block per channel d; 256 threads x 4 timesteps; Hillis-Steele over
// affine pairs (A,B): compose (A1,B1) then (A2,B2) -> (A1*A2, B1*A2+B2).
__global__ __launch_bounds__(256) void pos_scan_kernel(
    const float* __restrict__ h, float* __restrict__ x) {
    const int d = blockIdx.x;
    const int tid = threadIdx.x;
    float a[4], b[4];
    #pragma unroll
    for (int i = 0; i < 4; ++i) {
        int t = tid * 4 + i;
        float g  = h[(size_t)t * FF1_OUT + d];
        float lg = h[(size_t)t * FF1_OUT + D + d];
        a[i] = 1.f / (1.f + __expf(-g));
        b[i] = __expf(lg);
    }
    float A = ((a[0] * a[1]) * a[2]) * a[3];
    float B = ((b[0] * a[1] + b[1]) * a[2] + b[2]) * a[3] + b[3];

    __shared__ float sA[256], sB[256];
    sA[tid] = A; sB[tid] = B;
    __syncthreads();
    #pragma unroll
    for (int off = 1; off < 256; off <<= 1) {
        float selfA = sA[tid], selfB = sB[tid];
        float pA = 1.f, pB = 0.f;
        if (tid >= off) { pA = sA[tid - off]; pB = sB[tid - off]; }
        __syncthreads();
        sA[tid] = pA * selfA;
        sB[tid] = pB * selfA + selfB;
        __syncthreads();
    }
    float R = 1.f;
    if (tid > 0) R = sA[tid - 1] + sB[tid - 1];   // prefix applied to R=1
    #pragma unroll
    for (int i = 0; i < 4; ++i) {
        R = R * a[i] + b[i];
        x[(size_t)(tid * 4 + i) * D + d] += __logf(R);
    }
}

// ---------------------------------------------------- layernorm (bf16 out)
__global__ __launch_bounds__(256) void ln_kernel(
    const float* __restrict__ in, const float* __restrict__ g,
    const float* __restrict__ b, u16* __restrict__ out) {
    int row = blockIdx.x;
    int tid = threadIdx.x;
    const float* p = in + (size_t)row * D;
    float v0 = p[tid], v1 = p[tid + 256], v2 = p[tid + 512];

    __shared__ float red[8];
    float s = v0 + v1 + v2;
    #pragma unroll
    for (int o = 32; o > 0; o >>= 1) s += __shfl_down(s, o, 64);
    int wave = tid >> 6, lane = tid & 63;
    if (lane == 0) red[wave] = s;
    __syncthreads();
    float mean = (red[0] + red[1] + red[2] + red[3]) * (1.f / (float)D);

    float d0 = v0 - mean, d1 = v1 - mean, d2 = v2 - mean;
    float ss = d0 * d0 + d1 * d1 + d2 * d2;
    #pragma unroll
    for (int o = 32; o > 0; o >>= 1) ss += __shfl_down(ss, o, 64);
    if (lane == 0) red[4 + wave] = ss;
    __syncthreads();
    float var = (red[4] + red[5] + red[6] + red[7]) * (1.f / (float)D);
    float rstd = rsqrtf(var + 1e-5f);

    u16* o = out + (size_t)row * D;
    o[tid]       = f2bf(d0 * rstd * g[tid]       + b[tid]);
    o[tid + 256] = f2bf(d1 * rstd * g[tid + 256] + b[tid + 256]);
    o[tid + 512] = f2bf(d2 * rstd * g[tid + 512] + b[tid + 512]);
}

// ------------------------------------- weight convert+transpose fp32->bf16
__global__ __launch_bounds__(256) void wconv_kernel(
    const float* __restrict__ W, u16* __restrict__ WT, int N) {
    __shared__ float tile[32][33];
    const int z = blockIdx.z;
    W  += (size_t)z * 768 * N;
    WT += (size_t)z * N * 768;
    const int n0 = blockIdx.x * 32, k0 = blockIdx.y * 32;
    const int t = threadIdx.x;
    const int r = t >> 3, c4 = (t & 7) * 4;
    float4 v = *(const float4*)(W + (size_t)(k0 + r) * N + n0 + c4);
    tile[r][c4] = v.x; tile[r][c4 + 1] = v.y; tile[r][c4 + 2] = v.z; tile[r][c4 + 3] = v.w;
    __syncthreads();
    ushort4 o;
    o.x = f2bf(tile[c4][r]);     o.y = f2bf(tile[c4 + 1][r]);
    o.z = f2bf(tile[c4 + 2][r]); o.w = f2bf(tile[c4 + 3][r]);
    *(ushort4*)(WT + (size_t)(n0 + r) * 768 + k0 + c4) = o;
}

// ------------------------------------------------------------- MFMA GEMM
template <bool BF16B>
__global__ __launch_bounds__(256) void gemm_kernel(
    const u16* __restrict__ A, const void* __restrict__ Bv,
    const float* __restrict__ bias, const float* __restrict__ Cin,
    float* __restrict__ C, int N) {
    constexpr int K = 768;
    __shared__ __align__(16) u16 As[128 * 32];
    __shared__ __align__(16) u16 Bs[128 * 32];
    const int tid = threadIdx.x;
    const int w = tid >> 6, lane = tid & 63;
    const int m0 = blockIdx.y * 128, n0 = blockIdx.x * 128;
    const int wm = (w >> 1) * 64, wn = (w & 1) * 64;

    f32x4 acc[4][4] = {};

    const int rA = w * 32 + (lane >> 2);
    const int cA = (lane & 3) * 8;
    const int frow = lane & 15;
    const int fko = (lane >> 4) * 8;

    for (int k0 = 0; k0 < K; k0 += 32) {
        {
            const u16* g0 = A + (size_t)(m0 + rA) * K + k0 + cA;
            async_copy16(g0, (char*)As + w * 2048);
            async_copy16(g0 + (size_t)16 * K, (char*)As + w * 2048 + 1024);
        }
        if (BF16B) {
            const u16* B = (const u16*)Bv;
            const u16* g0 = B + (size_t)(n0 + rA) * K + k0 + cA;
            async_copy16(g0, (char*)Bs + w * 2048);
            async_copy16(g0 + (size_t)16 * K, (char*)Bs + w * 2048 + 1024);
        } else {
            const float* B = (const float*)Bv;
            const int r = tid >> 1, half = tid & 1;
            const float* src = B + (size_t)(n0 + r) * K + k0 + half * 16;
            float4 v0 = *(const float4*)(src);
            float4 v1 = *(const float4*)(src + 4);
            float4 v2 = *(const float4*)(src + 8);
            float4 v3 = *(const float4*)(src + 12);
            unsigned p0 = (unsigned)f2bf(v0.x) | ((unsigned)f2bf(v0.y) << 16);
            unsigned p1 = (unsigned)f2bf(v0.z) | ((unsigned)f2bf(v0.w) << 16);
            unsigned p2 = (unsigned)f2bf(v1.x) | ((unsigned)f2bf(v1.y) << 16);
            unsigned p3 = (unsigned)f2bf(v1.z) | ((unsigned)f2bf(v1.w) << 16);
            unsigned p4 = (unsigned)f2bf(v2.x) | ((unsigned)f2bf(v2.y) << 16);
            unsigned p5 = (unsigned)f2bf(v2.z) | ((unsigned)f2bf(v2.w) << 16);
            unsigned p6 = (unsigned)f2bf(v3.x) | ((unsigned)f2bf(v3.y) << 16);
            unsigned p7 = (unsigned)f2bf(v3.z) | ((unsigned)f2bf(v3.w) << 16);
            u16* dst = Bs + r * 32 + half * 16;
            *(uint4*)(dst)     = make_uint4(p0, p1, p2, p3);
            *(uint4*)(dst + 8) = make_uint4(p4, p5, p6, p7);
        }
        __syncthreads();

        bf16x8 af[4], bfr[4];
        #pragma unroll
        for (int i = 0; i < 4; ++i)
            af[i] = *(const bf16x8*)(As + (wm + i * 16 + frow) * 32 + fko);
        #pragma unroll
        for (int j = 0; j < 4; ++j)
            bfr[j] = *(const bf16x8*)(Bs + (wn + j * 16 + frow) * 32 + fko);
        #pragma unroll
        for (int i = 0; i < 4; ++i)
            #pragma unroll
            for (int j = 0; j < 4; ++j)
                acc[i][j] = __builtin_amdgcn_mfma_f32_16x16x32_bf16(af[i], bfr[j], acc[i][j], 0, 0, 0);
        __syncthreads();
    }

    const int crow = wm + (lane >> 4) * 4;
    const int ccol = wn + (lane & 15);
    #pragma unroll
    for (int j = 0; j < 4; ++j) {
        int col = n0 + ccol + j * 16;
        float bj = bias ? bias[col] : 0.f;
        #pragma unroll
        for (int i = 0; i < 4; ++i) {
            #pragma unroll
            for (int r = 0; r < 4; ++r) {
                int row = m0 + crow + i * 16 + r;
                size_t off = (size_t)row * N + col;
                float v = acc[i][j][r] + bj;
                if (Cin) v += Cin[off];
                C[off] = v;
            }
        }
    }
}

// ------------------------------------------------- MFMA flash attention
// Linear-space causal attention with exp features.
// Per block: head, 64 Q-rows. Waves own 16-row strips. s-tiles of 64.
// A = eQ*eK^T (mfma) -> mask -> LDS (bf16, swizzled) -> O += A*V, Z += A*1.
__global__ __launch_bounds__(256) void attn_kernel(
    const float* __restrict__ y, u16* __restrict__ att) {
    const int tb = blockIdx.x, head = blockIdx.y;
    const int tid = threadIdx.x, w = tid >> 6, lane = tid & 63;
    const int q = lane >> 4, cl = lane & 15;
    const int t0 = tb * 64;

    __shared__ __align__(16) u16 Qs[64 * 32];
    __shared__ __align__(16) u16 Ks[64 * 32];
    __shared__ __align__(16) u16 Vt[32 * 64];
    __shared__ __align__(16) u16 As[4][16 * 64];
    u16* As_w = As[w];

    bf16x8 ones8;
    #pragma unroll
    for (int i = 0; i < 8; ++i) ones8[i] = (short)0x3F80;

    f32x4 accO[2] = {};
    f32x4 accZ = {};

    // stage eQ (once)
    #pragma unroll
    for (int i = 0; i < 2; ++i) {
        int e = tid + i * 256;
        int row = e >> 3, c4 = (e & 7) * 4;
        float4 v = *(const float4*)(y + (size_t)(t0 + row) * QKV_OUT + head * 96 + c4);
        ushort4 o;
        o.x = f2bf(__expf(v.x)); o.y = f2bf(__expf(v.y));
        o.z = f2bf(__expf(v.z)); o.w = f2bf(__expf(v.w));
        *(ushort4*)(Qs + row * 32 + c4) = o;
    }

    for (int sb = 0; sb <= tb; ++sb) {
        const int s0 = sb * 64;
        // stage eK row-major, eV transposed+swizzled
        #pragma unroll
        for (int i = 0; i < 2; ++i) {
            int e = tid + i * 256;
            int row = e >> 3, c4 = (e & 7) * 4;
            const float* src = y + (size_t)(s0 + row) * QKV_OUT + head * 96;
            float4 kv = *(const float4*)(src + 32 + c4);
            ushort4 o;
            o.x = f2bf(__expf(kv.x)); o.y = f2bf(__expf(kv.y));
            o.z = f2bf(__expf(kv.z)); o.w = f2bf(__expf(kv.w));
            *(ushort4*)(Ks + row * 32 + c4) = o;
            float4 vv = *(const float4*)(src + 64 + c4);
            float ev[4] = {__expf(vv.x), __expf(vv.y), __expf(vv.z), __expf(vv.w)};
            #pragma unroll
            for (int n = 0; n < 4; ++n) {
                int j = c4 + n;
                Vt[j * 64 + (((row >> 4) ^ (j & 3)) * 16) + (row & 15)] = f2bf(ev[n]);
            }
        }
        __syncthreads();

        // A strip = eQ(16) * eK^T(64)
        bf16x8 af_q = *(const bf16x8*)(Qs + (w * 16 + cl) * 32 + q * 8);
        f32x4 aqk[4];
        #pragma unroll
        for (int nt = 0; nt < 4; ++nt) {
            bf16x8 bk = *(const bf16x8*)(Ks + (nt * 16 + cl) * 32 + q * 8);
            aqk[nt] = __builtin_amdgcn_mfma_f32_16x16x32_bf16(af_q, bk, (f32x4){0.f, 0.f, 0.f, 0.f}, 0, 0, 0);
        }
        // mask + write A strip to LDS (bf16, quad-XOR swizzle, 2-way max)
        #pragma unroll
        for (int nt = 0; nt < 4; ++nt) {
            #pragma unroll
            for (int reg = 0; reg < 4; ++reg) {
                int r = q * 4 + reg;
                int tg = t0 + w * 16 + r;
                int cg = s0 + nt * 16 + cl;
                float v = (cg <= tg) ? aqk[nt][reg] : 0.f;
                As_w[r * 64 + ((nt ^ q) * 16) + cl] = f2bf(v);
            }
        }
        // read A fragments (same-wave DS ordering), then O/Z mfma
        bf16x8 af_a[2];
        #pragma unroll
        for (int kt = 0; kt < 2; ++kt) {
            int blk = (kt * 2 + (q >> 1)) ^ (cl >> 2);
            af_a[kt] = *(const bf16x8*)(As_w + cl * 64 + blk * 16 + (q & 1) * 8);
        }
        #pragma unroll
        for (int kt = 0; kt < 2; ++kt)
            accZ = __builtin_amdgcn_mfma_f32_16x16x32_bf16(af_a[kt], ones8, accZ, 0, 0, 0);
        #pragma unroll
        for (int nt = 0; nt < 2; ++nt) {
            #pragma unroll
            for (int kt = 0; kt < 2; ++kt) {
                int j = nt * 16 + cl;
                int blk = (kt * 2 + (q >> 1)) ^ (j & 3);
                bf16x8 bv = *(const bf16x8*)(Vt + j * 64 + blk * 16 + (q & 1) * 8);
                accO[nt] = __builtin_amdgcn_mfma_f32_16x16x32_bf16(af_a[kt], bv, accO[nt], 0, 0, 0);
            }
        }
        __syncthreads();
    }

    // epilogue: att = log(O) - log(Z)
    #pragma unroll
    for (int nt = 0; nt < 2; ++nt) {
        #pragma unroll
        for (int reg = 0; reg < 4; ++reg) {
            int t = t0 + w * 16 + q * 4 + reg;
            int j = nt * 16 + cl;
            att[(size_t)t * D + head * 32 + j] = f2bf(__logf(accO[nt][reg]) - __logf(accZ[reg]));
        }
    }
}

// --------------------------------------------------------------------- GLU
__global__ __launch_bounds__(256) void glu_kernel(
    const float* __restrict__ z, u16* __restrict__ zg) {
    int idx = blockIdx.x * 256 + threadIdx.x;
    int t = idx / D, d = idx - t * D;
    float a = z[(size_t)t * FF1_OUT + d];
    float g = z[(size_t)t * FF1_OUT + D + d];
    zg[idx] = f2bf(a * (1.f / (1.f + __expf(-g))));
}

// ------------------------------------------------------------------ launch
extern "C" void kernel_launch(void* const* d_in, const int* in_sizes, int n_in,
                              void* d_out, int out_size, void* d_ws, size_t ws_size,
                              hipStream_t stream) {
    const int*   tok     = (const int*)d_in[0];
    const float* embed_w = (const float*)d_in[1];
    const float* pos_w   = (const float*)d_in[2];
    const float* pos_b   = (const float*)d_in[3];
    const float* ln1_g   = (const float*)d_in[4];
    const float* ln1_b   = (const float*)d_in[5];
    const float* qkv_w   = (const float*)d_in[6];
    const float* qkv_b   = (const float*)d_in[7];
    const float* ff_w1   = (const float*)d_in[8];
    const float* ff_b1   = (const float*)d_in[9];
    const float* ff_w2   = (const float*)d_in[10];
    const float* lnf_g   = (const float*)d_in[11];
    const float* lnf_b   = (const float*)d_in[12];
    float* out = (float*)d_out;

    char* base = (char*)d_ws;
    float* X    = (float*)(base);
    u16*   XB   = (u16*)  (base + 3145728);
    float* Y    = (float*)(base + 4718592);
    u16*   LNX  = (u16*)  (base + 14155776);
    u16*   ATT  = (u16*)  (base + 15728640);
    u16*   ZG   = (u16*)  (base + 17301504);
    u16*   posT = (u16*)  (base + 18874368);
    u16*   qkvT = (u16*)  (base + 21233664);
    u16*   ff1T = (u16*)  (base + 63700992);
    u16*   ff2T = (u16*)  (base + 92012544);

    wconv_kernel<<<dim3(48, 24, 1),  256, 0, stream>>>(pos_w, posT, 1536);
    wconv_kernel<<<dim3(72, 24, 12), 256, 0, stream>>>(qkv_w, qkvT, 2304);
    wconv_kernel<<<dim3(48, 24, 12), 256, 0, stream>>>(ff_w1, ff1T, 1536);
    wconv_kernel<<<dim3(24, 24, 12), 256, 0, stream>>>(ff_w2, ff2T, 768);

    embed_kernel<<<S, 256, 0, stream>>>(tok, embed_w, X, XB);

    gemm_kernel<true><<<dim3(12, 8), 256, 0, stream>>>(XB, posT, pos_b, nullptr, Y, FF1_OUT);
    pos_scan_kernel<<<D, 256, 0, stream>>>(Y, X);

    for (int l = 0; l < L; ++l) {
        ln_kernel<<<S, 256, 0, stream>>>(X, ln1_g + (size_t)l * D, ln1_b + (size_t)l * D, LNX);
        gemm_kernel<true><<<dim3(18, 8), 256, 0, stream>>>(
            LNX, qkvT + (size_t)l * QKV_OUT * 768, qkv_b + (size_t)l * QKV_OUT, nullptr, Y, QKV_OUT);
        attn_kernel<<<dim3(16, NH), 256, 0, stream>>>(Y, ATT);
        gemm_kernel<true><<<dim3(12, 8), 256, 0, stream>>>(
            ATT, ff1T + (size_t)l * FF1_OUT * 768, ff_b1 + (size_t)l * FF1_OUT, nullptr, Y, FF1_OUT);
        glu_kernel<<<(S * D) / 256, 256, 0, stream>>>(Y, ZG);
        gemm_kernel<true><<<dim3(6, 8), 256, 0, stream>>>(
            ZG, ff2T + (size_t)l * D * 768, nullptr, X, X, D);
    }

    ln_kernel<<<S, 256, 0, stream>>>(X, lnf_g, lnf_b, LNX);
    gemm_kernel<false><<<dim3(393, 8), 256, 0, stream>>>(LNX, embed_w, nullptr, nullptr, out, V_SZ);
}